// Round 1
// 339.858 us; speedup vs baseline: 1.0026x; 1.0026x over previous
//
#include <hip/hip_runtime.h>

#define DDIM 256
#define NEDGE 4096
#define SLEN 64
#define NNODE 1024
#define ROWS 65536

typedef short s16x8 __attribute__((ext_vector_type(8)));
typedef float f32x4 __attribute__((ext_vector_type(4)));

static __device__ __forceinline__ unsigned short f2bf(float f){
  union { float f; unsigned u; } v; v.f = f;
  unsigned r = v.u + 0x7FFFu + ((v.u >> 16) & 1u);
  return (unsigned short)(r >> 16);
}

static __device__ __forceinline__ void gl2lds16(const unsigned short* g, unsigned short* l){
  __builtin_amdgcn_global_load_lds((const __attribute__((address_space(1))) unsigned int*)g,
                                   (__attribute__((address_space(3))) unsigned int*)l, 16, 0, 0);
}

// ---------------- setup: weight prep + lengths + CSR (folded), all 256-thread blocks ----------------
__global__ __launch_bounds__(256) void setup_kernel(const float* wq, const float* wk, const float* wv, const float* wo,
                                                    const float* bq, const float* bk, const float* bv,
                                                    const float* masks, const int* eidx,
                                                    unsigned short* Wqkv, unsigned short* Wo_t, float* qkvb,
                                                    int* lenp, int* startp, int* order, int* degp, int* elist){
  __shared__ int deg[NNODE];
  __shared__ int buf[256];
  __shared__ int hist[65];
  __shared__ int cur[NNODE];
  int bid = blockIdx.x, tid = threadIdx.x;
  if (bid < 1028){
    int idx = bid*256 + tid;
    if (idx < 196608){
      int mat = idx >> 16;
      int rem = idx & 65535;
      int n = rem >> 8, k = rem & 255;
      const float* W = (mat==0)?wq:(mat==1)?wk:wv;
      Wqkv[(size_t)(mat*256 + n)*256 + k] = f2bf(W[k*256 + n]);
    } else if (idx < 262144){
      int rem = idx - 196608;
      int n = rem >> 8, k = rem & 255;
      Wo_t[(size_t)n*256 + k] = f2bf(wo[k*256 + n]);
    } else if (idx < 262912){
      int i = idx - 262144;
      qkvb[i] = (i < 256) ? bq[i] : (i < 512) ? bk[i-256] : bv[i-512];
    }
  } else if (bid < 1284){
    int lane = tid & 63;
    int node = (bid - 1028)*4 + (tid >> 6);
    unsigned long long b = __ballot(masks[node*SLEN + lane] > 0.f);
    if (lane == 0) lenp[node] = __popcll(b);
  } else {
    // CSR build: degree + scan + degree-sort + fill, one 256-thread block
    int t = tid;
    #pragma unroll
    for (int i=0;i<4;i++) deg[i*256 + t] = 0;
    if (t < 65) hist[t] = 0;
    __syncthreads();
    #pragma unroll
    for (int i=0;i<16;i++) atomicAdd(&deg[eidx[i*256 + t]], 1);
    __syncthreads();
    int d[4]; int s = 0;
    #pragma unroll
    for (int j=0;j<4;j++){ d[j] = deg[t*4 + j]; s += d[j]; }
    buf[t] = s;
    __syncthreads();
    for (int off=1; off<256; off<<=1){
      int v = (t >= off) ? buf[t-off] : 0;
      __syncthreads();
      buf[t] += v;
      __syncthreads();
    }
    int run = buf[t] - s;
    #pragma unroll
    for (int j=0;j<4;j++){
      int node = t*4 + j;
      startp[node] = run; degp[node] = d[j]; cur[node] = run;
      run += d[j];
      int dc = d[j] > 64 ? 64 : d[j];
      atomicAdd(&hist[dc], 1);
    }
    __syncthreads();
    if (t == 0){
      int acc = 0;
      for (int i=64;i>=0;i--){ int h = hist[i]; hist[i] = acc; acc += h; }
    }
    __syncthreads();
    #pragma unroll
    for (int j=0;j<4;j++){
      int node = t*4 + j;
      int dc = d[j] > 64 ? 64 : d[j];
      int pos = atomicAdd(&hist[dc], 1);
      order[pos] = node;
    }
    __syncthreads();
    #pragma unroll
    for (int i=0;i<16;i++){
      int e = i*256 + t;
      int sn = eidx[e];
      int p = atomicAdd(&cur[sn], 1);
      elist[p] = eidx[NEDGE + e];
    }
  }
}

// ---------------- fused LN + QKV GEMM: 1 block per node, A resident in LDS, B dbuf-streamed ----------------
__global__ __launch_bounds__(256) void qkvln_kernel(const float* nf, const float* lnw, const float* lnb,
                                                    const unsigned short* Wqkv, const float* qkvb, const int* lenp,
                                                    unsigned short* qb, unsigned short* kb_, unsigned short* vt){
  __shared__ __align__(16) unsigned short As[16384];   // [kc 4][row 64][col 64], XOR-swizzled
  __shared__ __align__(16) unsigned short Bs[2][8192]; // [brow 128][k 64], XOR-swizzled
  int tid = threadIdx.x;
  int lane = tid & 63, wid = tid >> 6, m = lane & 15, quad = lane >> 4;
  int node = blockIdx.x;
  int row0 = node * 64;
  int qtm = (lenp[node] + 15) >> 4;   // valid 16-row tiles (1..4)
  int rw = (wid & 1) * 32, cw = (wid >> 1) * 64;
  int t0 = rw >> 4;

  // ---- LN of this node's valid rows, written straight into swizzled As ----
  if (wid < qtm){
    float4 w4 = ((const float4*)lnw)[lane];
    float4 b4 = ((const float4*)lnb)[lane];
    int chunk = lane >> 4;              // k-chunk this lane's 4 cols live in
    int slot0 = (lane & 15) >> 1;       // 8-col group within chunk
    int half  = (lane & 1) * 4;         // ushort offset within the group
    const float4* src = (const float4*)(nf + (size_t)(row0 + wid*16)*DDIM);
    #pragma unroll
    for (int r=0; r<16; r++){
      int row = wid*16 + r;
      float4 x4 = src[r*64 + lane];
      float s  = x4.x + x4.y + x4.z + x4.w;
      float sq = x4.x*x4.x + x4.y*x4.y + x4.z*x4.z + x4.w*x4.w;
      #pragma unroll
      for (int off=1; off<64; off<<=1){ s += __shfl_xor(s, off); sq += __shfl_xor(sq, off); }
      float mu  = s  * (1.0f/DDIM);
      float var = sq * (1.0f/DDIM) - mu*mu;
      float rs  = rsqrtf(var + 1e-5f);
      ushort4 o;
      o.x = f2bf((x4.x - mu)*rs*w4.x + b4.x);
      o.y = f2bf((x4.y - mu)*rs*w4.y + b4.y);
      o.z = f2bf((x4.z - mu)*rs*w4.z + b4.z);
      o.w = f2bf((x4.w - mu)*rs*w4.w + b4.w);
      *(ushort4*)(As + chunk*4096 + row*64 + ((slot0 ^ (row&7))<<3) + half) = o;
    }
  }

  // prologue: stage B tile for phase 0 (cb=0, kc=0)
  #pragma unroll
  for (int i=0;i<4;i++){
    int cid = i*256 + tid, brow = cid >> 3, c8 = cid & 7;
    gl2lds16(Wqkv + (size_t)brow*DDIM + ((c8 ^ (brow&7))<<3), Bs[0] + cid*8);
  }

  f32x4 acc[8];
  #pragma unroll
  for (int i=0;i<8;i++) acc[i] = (f32x4){0.f,0.f,0.f,0.f};

  // 24 phases = 6 col-blocks x 4 k-chunks; one barrier/phase, stage(p+1) overlaps compute(p)
  for (int p=0; p<24; p++){
    int cb = p >> 2, kc = p & 3;
    __syncthreads();  // drains vmcnt: stage(p) complete; all waves done reading Bs[(p+1)&1]
    if (p+1 < 24){
      int cb1 = (p+1) >> 2, kc1 = (p+1) & 3;
      const unsigned short* bsrc = Wqkv + (size_t)cb1*128*DDIM + kc1*64;
      unsigned short* bdst = Bs[(p+1)&1];
      #pragma unroll
      for (int i=0;i<4;i++){
        int cid = i*256 + tid, brow = cid >> 3, c8 = cid & 7;
        gl2lds16(bsrc + (size_t)brow*DDIM + ((c8 ^ (brow&7))<<3), bdst + cid*8);
      }
    }
    const unsigned short* Asc = As + kc*4096;
    const unsigned short* Bsc = Bs[p&1];
    #pragma unroll
    for (int ks=0; ks<2; ks++){
      int sw = ((ks*4 + quad) ^ (m&7)) << 3;
      s16x8 af[2], bf[4];
      #pragma unroll
      for (int mt=0;mt<2;mt++) if (t0 + mt < qtm) af[mt] = *(const s16x8*)(Asc + (rw + mt*16 + m)*64 + sw);
      #pragma unroll
      for (int nt=0;nt<4;nt++) bf[nt] = *(const s16x8*)(Bsc + (cw + nt*16 + m)*64 + sw);
      #pragma unroll
      for (int mt=0;mt<2;mt++) if (t0 + mt < qtm)
        #pragma unroll
        for (int nt=0;nt<4;nt++)
          acc[mt*4+nt] = __builtin_amdgcn_mfma_f32_16x16x32_bf16(af[mt], bf[nt], acc[mt*4+nt], 0,0,0);
    }
    if (kc == 3){
      int col0 = cb*128;
      #pragma unroll
      for (int nt=0;nt<4;nt++){
        int cg = col0 + cw + nt*16 + m;
        int mat = cg >> 8, col = cg & 255;
        float bb = qkvb[cg];
        if (mat < 2){
          unsigned short* ob = (mat==0)?qb:kb_;
          #pragma unroll
          for (int mt=0;mt<2;mt++) if (t0 + mt < qtm)
            #pragma unroll
            for (int r=0;r<4;r++){
              int row = row0 + rw + mt*16 + quad*4 + r;
              ob[(size_t)row*DDIM + col] = f2bf(acc[mt*4+nt][r] + bb);
            }
        } else {
          #pragma unroll
          for (int mt=0;mt<2;mt++) if (t0 + mt < qtm){
            int tok0 = rw + mt*16 + quad*4;
            ushort4 pk;
            pk.x = f2bf(acc[mt*4+nt][0] + bb);
            pk.y = f2bf(acc[mt*4+nt][1] + bb);
            pk.z = f2bf(acc[mt*4+nt][2] + bb);
            pk.w = f2bf(acc[mt*4+nt][3] + bb);
            *(ushort4*)(vt + ((size_t)node*256 + col)*64 + tok0) = pk;
          }
        }
      }
      #pragma unroll
      for (int i=0;i<8;i++) acc[i] = (f32x4){0.f,0.f,0.f,0.f};
    }
  }
}

// ---------------- attention: block=(src,head), 4 waves=q-tiles, all-async dbuf staging ----------------
__global__ __launch_bounds__(256) void attn_kernel(const unsigned short* qb, const unsigned short* kbuf,
                                                   const unsigned short* vtb, const int* lenp,
                                                   const int* startp, const int* degp, const int* elist,
                                                   const int* order, unsigned short* ctxb){
  __shared__ __align__(16) unsigned short Kt[2][4096];
  __shared__ __align__(16) unsigned short Vt[2][4096];
  __shared__ unsigned short P[4096];
  int tid = threadIdx.x;
  int lane = tid & 63, wid = tid >> 6, m = lane & 15, quad = lane >> 4;
  int src = order[blockIdx.x], h = blockIdx.y;
  int ls = lenp[src];
  int qtm = (ls + 15) >> 4;
  int s0 = startp[src], dg = degp[src];
  bool active = wid < qtm;
  unsigned short* Pw = P + wid*1024;

  s16x8 qf0 = {0,0,0,0,0,0,0,0}, qf1 = {0,0,0,0,0,0,0,0};
  if (active){
    const unsigned short* qbase = qb + (size_t)(src*SLEN + wid*16 + m)*DDIM + h*64 + quad*8;
    qf0 = *(const s16x8*)(qbase);
    qf1 = *(const s16x8*)(qbase + 32);
  }
  f32x4 o[4];
  #pragma unroll
  for (int i=0;i<4;i++) o[i] = (f32x4){0.f,0.f,0.f,0.f};

  int dst0 = 0, dst1 = 0, ld0 = 0;
  if (dg > 0){
    dst0 = elist[s0];
    ld0 = lenp[dst0];
    int kch = ((ld0 + 15) >> 4) * 128;
    #pragma unroll
    for (int i=0;i<2;i++){
      int cid = i*256 + tid;
      if (i*256 + wid*64 < kch){
        int row = cid >> 3, c8 = cid & 7;
        gl2lds16(kbuf + (size_t)(dst0*SLEN + row)*DDIM + h*64 + ((c8 ^ (row&7))<<3), Kt[0] + cid*8);
      }
    }
    const unsigned short* vhead = vtb + ((size_t)dst0*256 + h*64)*64;
    #pragma unroll
    for (int i=0;i<2;i++){
      int cid = i*256 + tid, row = cid >> 3, c8 = cid & 7;
      gl2lds16(vhead + row*64 + ((c8 ^ (row&7))<<3), Vt[0] + cid*8);
    }
  }
  if (dg > 1) dst1 = elist[s0 + 1];
  __syncthreads();

  for (int ei=0; ei<dg; ei++){
    int cur = ei & 1, nxt = cur ^ 1;
    int dst2 = (ei+2 < dg) ? elist[s0 + ei + 2] : 0;
    int ld1 = 0;
    if (ei+1 < dg){
      ld1 = lenp[dst1];
      int kch = ((ld1 + 15) >> 4) * 128;
      #pragma unroll
      for (int i=0;i<2;i++){
        int cid = i*256 + tid;
        if (i*256 + wid*64 < kch){
          int row = cid >> 3, c8 = cid & 7;
          gl2lds16(kbuf + (size_t)(dst1*SLEN + row)*DDIM + h*64 + ((c8 ^ (row&7))<<3), Kt[nxt] + cid*8);
        }
      }
      const unsigned short* vhead = vtb + ((size_t)dst1*256 + h*64)*64;
      #pragma unroll
      for (int i=0;i<2;i++){
        int cid = i*256 + tid, row = cid >> 3, c8 = cid & 7;
        gl2lds16(vhead + row*64 + ((c8 ^ (row&7))<<3), Vt[nxt] + cid*8);
      }
    }
    int ktm = (ld0 + 15) >> 4;
    int ks2 = (ktm + 1) >> 1;
    if (active){
      f32x4 acc[4];
      #pragma unroll
      for (int i=0;i<4;i++) acc[i] = (f32x4){0.f,0.f,0.f,0.f};
      #pragma unroll
      for (int kt=0; kt<4; kt++) if (kt < ktm){
        int key = kt*16 + m;
        s16x8 b0 = *(const s16x8*)(Kt[cur] + key*64 + ((quad ^ (m&7))<<3));
        acc[kt] = __builtin_amdgcn_mfma_f32_16x16x32_bf16(qf0, b0, acc[kt], 0,0,0);
        s16x8 b1 = *(const s16x8*)(Kt[cur] + key*64 + (((4 + quad) ^ (m&7))<<3));
        acc[kt] = __builtin_amdgcn_mfma_f32_16x16x32_bf16(qf1, b1, acc[kt], 0,0,0);
      }
      #pragma unroll
      for (int r=0; r<4; r++){
        float x[4];
        #pragma unroll
        for (int kt=0; kt<4; kt++)
          x[kt] = (kt < ktm && kt*16 + m < ld0) ? __expf(acc[kt][r]*0.125f) : 0.f;
        float s = x[0] + x[1] + x[2] + x[3];
        for (int off=1; off<16; off<<=1) s += __shfl_xor(s, off);
        float inv = 1.0f / s;
        int q = quad*4 + r;
        #pragma unroll
        for (int kt=0; kt<4; kt++) if (kt < 2*ks2){
          int key = kt*16 + m;
          Pw[q*64 + (((key>>3)^(q&7))<<3) + (key&7)] = f2bf(x[kt]*inv);
        }
      }
      #pragma unroll
      for (int ks=0; ks<2; ks++) if (ks < ks2){
        s16x8 pa = *(const s16x8*)(Pw + m*64 + ((((ks*4+quad))^(m&7))<<3));
        #pragma unroll
        for (int dt=0; dt<4; dt++){
          int d = dt*16 + m;
          s16x8 vf = *(const s16x8*)(Vt[cur] + d*64 + (((ks*4+quad)^(d&7))<<3));
          o[dt] = __builtin_amdgcn_mfma_f32_16x16x32_bf16(pa, vf, o[dt], 0,0,0);
        }
      }
    }
    dst0 = dst1; ld0 = ld1; dst1 = dst2;
    __syncthreads();
  }
  if (active){
    #pragma unroll
    for (int dt=0; dt<4; dt++){
      int col = h*64 + dt*16 + m;
      #pragma unroll
      for (int r=0; r<4; r++){
        int row = src*SLEN + wid*16 + quad*4 + r;
        ctxb[(size_t)row*DDIM + col] = f2bf(o[dt][r]);
      }
    }
  }
}

// ---------------- output GEMM, mask-aware: valid tiles full path, masked tiles write zeros ----------------
__global__ __launch_bounds__(256) void out_kernel(const unsigned short* ctxb, const unsigned short* Wo_t,
                                                  const float* bo, const float* nf, const float* masks,
                                                  const int* lenp, float* out){
  __shared__ __align__(16) unsigned short As[4096];
  __shared__ __align__(16) unsigned short Bs[8192];
  int tid = threadIdx.x;
  int lane = tid & 63, wid = tid >> 6, m = lane & 15, quad = lane >> 4;
  int row0 = blockIdx.x * 64;
  int node = row0 >> 6;
  int qtm = (lenp[node] + 15) >> 4;
  int vrows = qtm << 4;
  int col0 = blockIdx.y * 128;
  int rw = (wid & 1) * 32, cw = (wid >> 1) * 64;
  int t0 = rw >> 4;
  f32x4 acc[8];
  #pragma unroll
  for (int i=0;i<8;i++) acc[i] = (f32x4){0.f,0.f,0.f,0.f};
  for (int kc = 0; kc < 4; kc++){
    __syncthreads();
    #pragma unroll
    for (int i=0;i<2;i++){
      if (i*32 + wid*8 < vrows){
        int cid = i*256 + tid, row = cid >> 3, c8 = cid & 7;
        gl2lds16(ctxb + (size_t)(row0 + row)*DDIM + kc*64 + ((c8 ^ (row&7))<<3), As + cid*8);
      }
    }
    #pragma unroll
    for (int i=0;i<4;i++){
      int cid = i*256 + tid, row = cid >> 3, c8 = cid & 7;
      gl2lds16(Wo_t + (size_t)(col0 + row)*DDIM + kc*64 + ((c8 ^ (row&7))<<3), Bs + cid*8);
    }
    __syncthreads();
    #pragma unroll
    for (int ks=0; ks<2; ks++){
      int sw = ((ks*4 + quad) ^ (m&7)) << 3;
      s16x8 af[2], bf[4];
      #pragma unroll
      for (int mt=0;mt<2;mt++) if (t0 + mt < qtm) af[mt] = *(const s16x8*)(As + (rw + mt*16 + m)*64 + sw);
      #pragma unroll
      for (int nt=0;nt<4;nt++) bf[nt] = *(const s16x8*)(Bs + (cw + nt*16 + m)*64 + sw);
      #pragma unroll
      for (int mt=0;mt<2;mt++) if (t0 + mt < qtm)
        #pragma unroll
        for (int nt=0;nt<4;nt++)
          acc[mt*4+nt] = __builtin_amdgcn_mfma_f32_16x16x32_bf16(af[mt], bf[nt], acc[mt*4+nt], 0,0,0);
    }
  }
  #pragma unroll
  for (int nt=0;nt<4;nt++){
    int col = col0 + cw + nt*16 + m;
    float bb = bo[col];
    #pragma unroll
    for (int mt=0;mt<2;mt++){
      if (t0 + mt < qtm){
        #pragma unroll
        for (int r=0;r<4;r++){
          int row = row0 + rw + mt*16 + quad*4 + r;
          float v = acc[mt*4+nt][r] + bb + nf[(size_t)row*DDIM + col];
          out[(size_t)row*DDIM + col] = v * masks[row];
        }
      } else {
        #pragma unroll
        for (int r=0;r<4;r++){
          int row = row0 + rw + mt*16 + quad*4 + r;
          out[(size_t)row*DDIM + col] = 0.f;
        }
      }
    }
  }
}

extern "C" void kernel_launch(void* const* d_in, const int* in_sizes, int n_in,
                              void* d_out, int out_size, void* d_ws, size_t ws_size,
                              hipStream_t stream){
  const float* nf    = (const float*)d_in[0];
  const float* masks = (const float*)d_in[1];
  const float* lnw   = (const float*)d_in[2];
  const float* lnb   = (const float*)d_in[3];
  const float* wq    = (const float*)d_in[4];
  const float* bq    = (const float*)d_in[5];
  const float* wk    = (const float*)d_in[6];
  const float* bk    = (const float*)d_in[7];
  const float* wv    = (const float*)d_in[8];
  const float* bv    = (const float*)d_in[9];
  const float* wo    = (const float*)d_in[10];
  const float* bo    = (const float*)d_in[11];
  const int*   eidx  = (const int*)d_in[13];
  float* out = (float*)d_out;

  char* ws = (char*)d_ws;
  const size_t B = (size_t)ROWS * DDIM * 2;
  unsigned short* qb   = (unsigned short*)(ws + B);
  unsigned short* kb   = (unsigned short*)(ws + 2*B);
  unsigned short* vt   = (unsigned short*)(ws + 3*B);   // V transposed: [node][col 256][token 64]
  unsigned short* ctxb = (unsigned short*)(ws + 4*B);
  char* wp = ws + 5*B;
  unsigned short* Wqkv = (unsigned short*)(wp);
  unsigned short* Wo_t = (unsigned short*)(wp + 393216);
  float* qkvb         = (float*)(wp + 524288);
  char* ip = wp + 528384;
  int* startp = (int*)(ip);
  int* lenp   = (int*)(ip + 4096);
  int* order  = (int*)(ip + 8192);
  int* degp   = (int*)(ip + 12288);
  int* elist  = (int*)(ip + 16384);

  setup_kernel<<<1285, 256, 0, stream>>>(wq, wk, wv, wo, bq, bk, bv, masks, eidx,
                                         Wqkv, Wo_t, qkvb, lenp, startp, order, degp, elist);
  qkvln_kernel<<<NNODE, 256, 0, stream>>>(nf, lnw, lnb, Wqkv, qkvb, lenp, qb, kb, vt);
  attn_kernel<<<dim3(NNODE, 4), 256, 0, stream>>>(qb, kb, vt, lenp, startp, degp, elist, order, ctxb);
  out_kernel<<<dim3(ROWS/64, 2), 256, 0, stream>>>(ctxb, Wo_t, bo, nf, masks, lenp, out);
}